// Round 11
// baseline (219.186 us; speedup 1.0000x reference)
//
#include <hip/hip_runtime.h>
#include <hip/hip_bf16.h>
#include <stdint.h>

typedef __bf16 bf16_t;
typedef __bf16 bf16x8 __attribute__((ext_vector_type(8)));
typedef float f32x4 __attribute__((ext_vector_type(4)));
typedef unsigned int u32x4 __attribute__((ext_vector_type(4)));

#define NB 4
#define NH 12
#define ND 64
#define NN 2048
#define NC 768
// M = NB*NN = 8192 rows; qkv cols = 3*NC = 2304

// async global->LDS, 16B per lane; lds dest = wave-uniform base + lane*16
__device__ __forceinline__ void async_copy16(const bf16_t* g, bf16_t* l) {
    __builtin_amdgcn_global_load_lds((__attribute__((address_space(1))) void*)(void*)g,
                                     (__attribute__((address_space(3))) void*)l, 16, 0, 0);
}

__device__ __forceinline__ unsigned pack_bf2(float a, float b) {
    union { bf16_t e[2]; unsigned u; } t;
    t.e[0] = (bf16_t)a;
    t.e[1] = (bf16_t)b;
    return t.u;
}

// ---------------- merged cast fp32 -> bf16 (3 segments), 4 elems/thread ----------------
__global__ void cast3_kernel(const float* __restrict__ s0, bf16_t* __restrict__ d0, int n0,
                             const float* __restrict__ s1, bf16_t* __restrict__ d1, int n1,
                             const float* __restrict__ s2, bf16_t* __restrict__ d2, int n2) {
    int i = blockIdx.x * blockDim.x + threadIdx.x;   // float4 units
    const float* s;
    bf16_t* d;
    int j;
    if (i < n0)           { s = s0; d = d0; j = i; }
    else if (i < n0 + n1) { s = s1; d = d1; j = i - n0; }
    else if (i < n0 + n1 + n2) { s = s2; d = d2; j = i - n0 - n1; }
    else return;
    float4 v = ((const float4*)s)[j];
    union { bf16_t e[4]; uint2 u; } t;
    t.e[0] = (bf16_t)v.x; t.e[1] = (bf16_t)v.y; t.e[2] = (bf16_t)v.z; t.e[3] = (bf16_t)v.w;
    ((uint2*)d)[j] = t.u;
}

// key permutation: key s (within 64-tile) -> V storage position
// pos bits {c5,c4,c3,c2,c1,c0} = {s5, s3, s2, s4, s1, s0}  (s0,s1 fixed -> +p stays consecutive)
__device__ __forceinline__ int vperm(int s) {
    return (s & 32) | (((s >> 2) & 3) << 3) | (((s >> 4) & 1) << 2) | (s & 3);
}

// GEMM/attn LDS tiles: [rows][8 chunks of 16B], XOR swizzle: data chunk c of row r
// lives at chunk position c ^ (r & 7). Measured conflict-free (SQ_LDS_BANK_CONFLICT=0).

// ---------------- QKV GEMM: [8192,2304] = X[8192,768] @ W[2304,768]^T + b ----------------
// R8 chunking kept: each XCD owns a 16m x 9n rectangle (n-fastest) -> panels L2-resident.
// R11: operand swap for Q/K blocks (t3<2, block-uniform since 768=6*128). mfma(bfr,af,acc)
// flips the C-layout so reg p traverses the FEATURE dim: Q/K epilogue becomes 16 uint2
// stores + float4 bias loads per thread (was 64 scalar 2B stores + scalar bias). A/B frag
// k-layouts are symmetric (same property attn's S^T=K.Q^T relies on), so LDS reads are
// unchanged. V blocks (t3==2) keep the proven unswapped path + vperm write verbatim.
// Q,K out bf16 [B,H,N,D] (Q pre-scaled by D^-0.5*log2e); V out bf16 [B,H,D,N] vperm'd.
__launch_bounds__(256)
__global__ void qkv_gemm_kernel(const bf16_t* __restrict__ X, const bf16_t* __restrict__ W,
                                const float* __restrict__ bias,
                                bf16_t* __restrict__ Q, bf16_t* __restrict__ K, bf16_t* __restrict__ V)
{
    __shared__ __align__(16) bf16_t sA[128 * 64];
    __shared__ __align__(16) bf16_t sB[128 * 64];
    const int tid  = threadIdx.x;
    const int lane = tid & 63;
    const int w    = tid >> 6;
    const int wm   = w & 1, wn = w >> 1;
    const int wg  = blockIdx.y * 64 + blockIdx.x;   // 0..1151
    const int xcd = wg & 7;
    const int idx = wg >> 3;                        // 0..143 = 16m x 9n
    const int ny  = (xcd & 1) * 9 + idx % 9;        // 0..17
    const int m0  = ((xcd >> 1) * 16 + idx / 9) * 128;
    const int n0  = ny * 128;
    const bool qk_swap = (ny < 12);                 // Q,K sections
    const int lrow = lane & 15;
    const int quad = lane >> 4;
    const int arow = lane >> 3;
    const int gch  = (lane & 7) ^ arow;   // swizzled source chunk

    f32x4 zero = {0.f, 0.f, 0.f, 0.f};
    f32x4 acc[4][4];
#pragma unroll
    for (int i = 0; i < 4; ++i)
#pragma unroll
        for (int j = 0; j < 4; ++j) acc[i][j] = zero;

    for (int kt = 0; kt < NC; kt += 64) {
        __syncthreads();
        for (int c = w; c < 16; c += 4) {
            async_copy16(X + (size_t)(m0 + c * 8 + arow) * NC + kt + gch * 8, sA + c * 512);
            async_copy16(W + (size_t)(n0 + c * 8 + arow) * NC + kt + gch * 8, sB + c * 512);
        }
        __syncthreads();
#pragma unroll
        for (int hh = 0; hh < 2; ++hh) {
            bf16x8 af[4], bfr[4];
#pragma unroll
            for (int i = 0; i < 4; ++i) {
                int r = wm * 64 + i * 16 + lrow;
                af[i] = *(const bf16x8*)(sA + r * 64 + (((hh * 4 + quad) ^ (r & 7)) * 8));
            }
#pragma unroll
            for (int j = 0; j < 4; ++j) {
                int r = wn * 64 + j * 16 + lrow;
                bfr[j] = *(const bf16x8*)(sB + r * 64 + (((hh * 4 + quad) ^ (r & 7)) * 8));
            }
            if (qk_swap) {
#pragma unroll
                for (int i = 0; i < 4; ++i)
#pragma unroll
                    for (int j = 0; j < 4; ++j)
                        acc[i][j] = __builtin_amdgcn_mfma_f32_16x16x32_bf16(bfr[j], af[i], acc[i][j], 0, 0, 0);
            } else {
#pragma unroll
                for (int i = 0; i < 4; ++i)
#pragma unroll
                    for (int j = 0; j < 4; ++j)
                        acc[i][j] = __builtin_amdgcn_mfma_f32_16x16x32_bf16(af[i], bfr[j], acc[i][j], 0, 0, 0);
            }
        }
    }

    const int colbase = n0 + wn * 64;       // 64-aligned -> t3,h uniform per wave
    const int t3 = colbase / NC;
    const int h  = (colbase % NC) / ND;
    const float qscale = 0.125f * 1.44269504088896340736f; // D^-0.5 * log2(e)

    if (t3 == 2) {
        // V path (unswapped acc): col(lane&15)=feature d, row(quad*4+p)=token
#pragma unroll
        for (int j = 0; j < 4; ++j) {
            const int d  = j * 16 + lrow;
            const float bv = bias[colbase + d];
#pragma unroll
            for (int i = 0; i < 4; ++i) {
                const int rowg = m0 + wm * 64 + i * 16 + quad * 4;
                const int bb = rowg >> 11;
                const int nn = rowg & 2047;
                union { bf16_t e[4]; uint2 u; } pk;
#pragma unroll
                for (int p = 0; p < 4; ++p) pk.e[p] = (bf16_t)(acc[i][j][p] + bv);
                const int pos = (nn & ~63) | vperm(nn & 63);
                *(uint2*)(V + ((size_t)(bb * NH + h) * ND + d) * NN + pos) = pk.u;
            }
        }
    } else {
        // Q/K path (swapped acc): col(lane&15)=token, row(quad*4+p)=feature d -> uint2
        bf16_t* outb = t3 ? K : Q;
        const float sc = (t3 == 0) ? qscale : 1.0f;
#pragma unroll
        for (int j = 0; j < 4; ++j) {
            const int dbase = j * 16 + quad * 4;
            const float4 bv4 = *(const float4*)(bias + colbase + dbase);
#pragma unroll
            for (int i = 0; i < 4; ++i) {
                const int rowg = m0 + wm * 64 + i * 16 + lrow;   // token
                const int bb = rowg >> 11;
                const int nn = rowg & 2047;
                union { bf16_t e[4]; uint2 u; } pk;
                pk.e[0] = (bf16_t)((acc[i][j][0] + bv4.x) * sc);
                pk.e[1] = (bf16_t)((acc[i][j][1] + bv4.y) * sc);
                pk.e[2] = (bf16_t)((acc[i][j][2] + bv4.z) * sc);
                pk.e[3] = (bf16_t)((acc[i][j][3] + bv4.w) * sc);
                *(uint2*)(outb + ((size_t)(bb * NH + h) * NN + nn) * ND + dbase) = pk.u;
            }
        }
    }
}

// ---------------- flash attention v6 (R5/R8/R10 measured-best, frozen): 8 waves x 16 q-rows ----------------
// R5 = 69.6us best; R8/R10 reproduced 70.1/71.6. Tri-buffer + counted vmcnt, conflict-free
// 16x16 LDS pattern. Across R0-R9 absolute pipe-busy conserved (VALU ~32us, MFMA ~24us)
// under 8 structural variants => HIP-level plateau. FROZEN.
#define WAIT_BAR(N)                                              \
    asm volatile("s_waitcnt vmcnt(" #N ")" ::: "memory");        \
    __builtin_amdgcn_sched_barrier(0);                           \
    __builtin_amdgcn_s_barrier();                                \
    __builtin_amdgcn_sched_barrier(0);

#define STAGE(BUF)                                               \
    {                                                            \
        async_copy16(kp, sK[BUF] + w * 512);                     \
        async_copy16(vp, sV[BUF] + w * 512);                     \
        kp += (size_t)64 * ND; vp += 64;                         \
    }

#define ATTN_COMPUTE(CUR)                                                                            \
    {                                                                                                \
        const bf16_t* sKh = sK[CUR];                                                                 \
        const bf16_t* sVh = sV[CUR];                                                                 \
        f32x4 s[4];                                                                                  \
        __builtin_amdgcn_s_setprio(1);                                                               \
        _Pragma("unroll")                                                                            \
        for (int blk = 0; blk < 4; ++blk) {                                                          \
            bf16x8 a0 = *(const bf16x8*)(sKh + off[blk][0]);                                         \
            bf16x8 a1 = *(const bf16x8*)(sKh + off[blk][1]);                                         \
            f32x4 z = zero;                                                                          \
            z = __builtin_amdgcn_mfma_f32_16x16x32_bf16(a0, qb0, z, 0, 0, 0);                        \
            z = __builtin_amdgcn_mfma_f32_16x16x32_bf16(a1, qb1, z, 0, 0, 0);                        \
            s[blk] = z;                                                                              \
        }                                                                                            \
        __builtin_amdgcn_s_setprio(0);                                                               \
        u32x4 pu0 = {0, 0, 0, 0}, pu1 = {0, 0, 0, 0};                                                \
        _Pragma("unroll")                                                                            \
        for (int blk = 0; blk < 4; ++blk) {                                                          \
            float e0 = __builtin_amdgcn_exp2f(s[blk][0]);                                            \
            float e1 = __builtin_amdgcn_exp2f(s[blk][1]);                                            \
            float e2 = __builtin_amdgcn_exp2f(s[blk][2]);                                            \
            float e3 = __builtin_amdgcn_exp2f(s[blk][3]);                                            \
            unsigned lo = pack_bf2(e0, e1), hi = pack_bf2(e2, e3);                                   \
            if (blk == 0)      { pu0[0] = lo; pu0[1] = hi; }                                         \
            else if (blk == 1) { pu0[2] = lo; pu0[3] = hi; }                                         \
            else if (blk == 2) { pu1[0] = lo; pu1[1] = hi; }                                         \
            else               { pu1[2] = lo; pu1[3] = hi; }                                         \
        }                                                                                            \
        bf16x8 pe0 = __builtin_bit_cast(bf16x8, pu0);                                                \
        bf16x8 pe1 = __builtin_bit_cast(bf16x8, pu1);                                                \
        __builtin_amdgcn_s_setprio(1);                                                               \
        lacc = __builtin_amdgcn_mfma_f32_16x16x32_bf16(ones, pe0, lacc, 0, 0, 0);                    \
        lacc = __builtin_amdgcn_mfma_f32_16x16x32_bf16(ones, pe1, lacc, 0, 0, 0);                    \
        _Pragma("unroll")                                                                            \
        for (int db = 0; db < 4; ++db) {                                                             \
            bf16x8 v0 = *(const bf16x8*)(sVh + off[db][0]);                                          \
            bf16x8 v1 = *(const bf16x8*)(sVh + off[db][1]);                                          \
            o[db] = __builtin_amdgcn_mfma_f32_16x16x32_bf16(v0, pe0, o[db], 0, 0, 0);                \
            o[db] = __builtin_amdgcn_mfma_f32_16x16x32_bf16(v1, pe1, o[db], 0, 0, 0);                \
        }                                                                                            \
        __builtin_amdgcn_s_setprio(0);                                                               \
    }

__launch_bounds__(512, 6)
__global__ void attn_kernel(const bf16_t* __restrict__ Q, const bf16_t* __restrict__ K,
                            const bf16_t* __restrict__ Vt, bf16_t* __restrict__ O)
{
    __shared__ __align__(16) bf16_t sK[3][64 * 64];
    __shared__ __align__(16) bf16_t sV[3][64 * 64];   // [d][pos]
    bf16_t* sQ = sK[0];   // Q tile (16 KB) overlays sK[0..1] during init
    const int tid  = threadIdx.x;
    const int lane = tid & 63;
    const int w    = tid >> 6;          // 0..7
    const int qt   = blockIdx.x;
    const int h    = blockIdx.y;
    const int b    = blockIdx.z;
    const int lrow = lane & 15;
    const int quad = lane >> 4;
    const int arow = lane >> 3;
    const int gch  = (lane & 7) ^ arow;
    const size_t head_off = (size_t)(b * NH + h) * NN * ND;
    const bf16_t* qh = Q  + head_off;
    const bf16_t* kh = K  + head_off;
    const bf16_t* vh = Vt + head_off;   // [d][n]

    // stage Q tile [128 x 64]: wave w stages chunks 2w, 2w+1
#pragma unroll
    for (int c = 0; c < 2; ++c)
        async_copy16(qh + (size_t)(qt * 128 + (w * 2 + c) * 8 + arow) * ND + gch * 8,
                     sQ + (w * 2 + c) * 512);
    __syncthreads();

    bf16x8 qb0, qb1;
    {
        int r = w * 16 + lrow;
        qb0 = *(const bf16x8*)(sQ + r * 64 + (((0 * 4 + quad) ^ (r & 7)) * 8));
        qb1 = *(const bf16x8*)(sQ + r * 64 + (((1 * 4 + quad) ^ (r & 7)) * 8));
    }
    __syncthreads();   // all waves done reading Q before K staging overwrites it

    // ones A-frag for the l row-sum MFMA
    bf16x8 ones;
#pragma unroll
    for (int p = 0; p < 8; ++p) ones[p] = (bf16_t)1.0f;

    // frag offsets (elements), rows blk*16+lrow, two 32-k halves
    int off[4][2];
#pragma unroll
    for (int blk = 0; blk < 4; ++blk) {
        int r = blk * 16 + lrow;
        off[blk][0] = r * 64 + ((quad ^ (r & 7)) * 8);
        off[blk][1] = r * 64 + (((4 + quad) ^ (r & 7)) * 8);
    }

    f32x4 zero = {0.f, 0.f, 0.f, 0.f};
    f32x4 o[4];
#pragma unroll
    for (int db = 0; db < 4; ++db) o[db] = zero;
    f32x4 lacc = zero;

    // staging: wave w covers rows [w*8, w*8+8) of each 64-row step tile
    const bf16_t* kp = kh + (size_t)(w * 8 + arow) * ND + gch * 8;
    const bf16_t* vp = vh + (size_t)(w * 8 + arow) * NN + gch * 8;

    // prologue: stage tiles 0,1 into bufs 0,1; wait only for tile 0 (tile 1 stays in flight)
    STAGE(0);
    STAGE(1);
    WAIT_BAR(2);

    int cur = 0;
    for (int it = 0; it < NN / 64 - 2; ++it) {
        int nxt = cur + 2; if (nxt >= 3) nxt -= 3;
        STAGE(nxt);                 // tile it+2; outstanding: 4 (tiles it+1, it+2)
        ATTN_COMPUTE(cur);          // tile it
        WAIT_BAR(2);                // my tile-(it+1) loads retired; it+2 stays in flight
        cur = (cur + 1 == 3) ? 0 : cur + 1;
    }
    // tile NN/64-2: nothing left to stage; ensure final tile landed before last step
    ATTN_COMPUTE(cur);
    WAIT_BAR(0);
    cur = (cur + 1 == 3) ? 0 : cur + 1;
    ATTN_COMPUTE(cur);

    // write attn out bf16 [B,N,C], col = h*64 + d; 4 consecutive d per store
    {
        const float rl = 1.0f / lacc[0];
        const int n = qt * 128 + w * 16 + lrow;
        const size_t rowoff = ((size_t)(b * NN + n)) * NC + h * ND;
#pragma unroll
        for (int db = 0; db < 4; ++db) {
            union { bf16_t e[4]; uint2 u; } pk;
#pragma unroll
            for (int p = 0; p < 4; ++p) pk.e[p] = (bf16_t)(o[db][p] * rl);
            *(uint2*)(O + rowoff + db * 16 + quad * 4) = pk.u;
        }
    }
}

// ---------------- proj GEMM: out[8192,768] = A[8192,768] @ W[768,768]^T + b (fp32) ----------------
// R8 measured-best: 128x128 tiles, BK=64 single-buffered, scalar fp32 stores. Grid (64,6)
// = 384 wgs. Capacity-aware XCD chunking: each XCD owns 8m x 6n (n-fastest): full W
// (1.2 MB) + 8 A-panels (1.6 MB) = 2.8 MB, fully L2-resident. FROZEN.
__launch_bounds__(256)
__global__ void proj_gemm_kernel(const bf16_t* __restrict__ A, const bf16_t* __restrict__ W,
                                 const float* __restrict__ bias, float* __restrict__ out)
{
    __shared__ __align__(16) bf16_t sA[128 * 64];
    __shared__ __align__(16) bf16_t sB[128 * 64];
    const int tid  = threadIdx.x;
    const int lane = tid & 63;
    const int w    = tid >> 6;
    const int wm   = w & 1, wn = w >> 1;
    const int wg  = blockIdx.y * 64 + blockIdx.x;   // 0..383
    const int xcd = wg & 7;
    const int idx = wg >> 3;                        // 0..47 = 8m x 6n
    const int m0  = (xcd * 8 + idx / 6) * 128;
    const int n0  = (idx % 6) * 128;
    const int lrow = lane & 15;
    const int quad = lane >> 4;
    const int arow = lane >> 3;
    const int gch  = (lane & 7) ^ arow;

    f32x4 zero = {0.f, 0.f, 0.f, 0.f};
    f32x4 acc[4][4];
#pragma unroll
    for (int i = 0; i < 4; ++i)
#pragma unroll
        for (int j = 0; j < 4; ++j) acc[i][j] = zero;

    for (int kt = 0; kt < NC; kt += 64) {
        __syncthreads();
        for (int c = w; c < 16; c += 4) {
            async_copy16(A + (size_t)(m0 + c * 8 + arow) * NC + kt + gch * 8, sA + c * 512);
            async_copy16(W + (size_t)(n0 + c * 8 + arow) * NC + kt + gch * 8, sB + c * 512);
        }
        __syncthreads();
#pragma unroll
        for (int hh = 0; hh < 2; ++hh) {
            bf16x8 af[4], bfr[4];
#pragma unroll
            for (int i = 0; i < 4; ++i) {
                int r = wm * 64 + i * 16 + lrow;
                af[i] = *(const bf16x8*)(sA + r * 64 + (((hh * 4 + quad) ^ (r & 7)) * 8));
            }
#pragma unroll
            for (int j = 0; j < 4; ++j) {
                int r = wn * 64 + j * 16 + lrow;
                bfr[j] = *(const bf16x8*)(sB + r * 64 + (((hh * 4 + quad) ^ (r & 7)) * 8));
            }
#pragma unroll
            for (int i = 0; i < 4; ++i)
#pragma unroll
                for (int j = 0; j < 4; ++j)
                    acc[i][j] = __builtin_amdgcn_mfma_f32_16x16x32_bf16(af[i], bfr[j], acc[i][j], 0, 0, 0);
        }
    }

#pragma unroll
    for (int j = 0; j < 4; ++j) {
        const int colg = n0 + wn * 64 + j * 16 + lrow;
        const float bv = bias[colg];
#pragma unroll
        for (int i = 0; i < 4; ++i) {
            const int rowg = m0 + wm * 64 + i * 16 + quad * 4;
#pragma unroll
            for (int p = 0; p < 4; ++p)
                out[(size_t)(rowg + p) * NC + colg] = acc[i][j][p] + bv;
        }
    }
}

extern "C" void kernel_launch(void* const* d_in, const int* in_sizes, int n_in,
                              void* d_out, int out_size, void* d_ws, size_t ws_size,
                              hipStream_t stream) {
    const float* x      = (const float*)d_in[0];
    const float* qkv_w  = (const float*)d_in[1];
    const float* qkv_b  = (const float*)d_in[2];
    const float* proj_w = (const float*)d_in[3];
    const float* proj_b = (const float*)d_in[4];
    float* out = (float*)d_out;

    char* ws = (char*)d_ws;
    bf16_t* xb    = (bf16_t*)ws; ws += (size_t)8192 * 768 * 2;
    bf16_t* wqkv  = (bf16_t*)ws; ws += (size_t)2304 * 768 * 2;
    bf16_t* wproj = (bf16_t*)ws; ws += (size_t)768 * 768 * 2;
    bf16_t* qb    = (bf16_t*)ws; ws += (size_t)NB * NH * NN * ND * 2;  // [B,H,N,D]
    bf16_t* kb    = (bf16_t*)ws; ws += (size_t)NB * NH * NN * ND * 2;  // [B,H,N,D]
    bf16_t* vb    = (bf16_t*)ws; ws += (size_t)NB * NH * NN * ND * 2;  // [B,H,D,N] permuted
    bf16_t* ab    = (bf16_t*)ws; ws += (size_t)8192 * 768 * 2;         // attn out [B,N,C]

    const int c0 = 8192 * 768 / 4, c1 = 2304 * 768 / 4, c2 = 768 * 768 / 4;
    cast3_kernel<<<(c0 + c1 + c2 + 255) / 256, 256, 0, stream>>>(x, xb, c0, qkv_w, wqkv, c1, proj_w, wproj, c2);

    qkv_gemm_kernel<<<dim3(8192 / 128, 2304 / 128), 256, 0, stream>>>(xb, wqkv, qkv_b, qb, kb, vb);
    attn_kernel<<<dim3(NN / 128, NH, NB), 512, 0, stream>>>(qb, kb, vb, ab);
    proj_gemm_kernel<<<dim3(8192 / 128, 768 / 128), 256, 0, stream>>>(ab, wproj, proj_b, out);
}

// Round 12
// 202.411 us; speedup vs baseline: 1.0829x; 1.0829x over previous
//
#include <hip/hip_runtime.h>
#include <hip/hip_bf16.h>
#include <stdint.h>

typedef __bf16 bf16_t;
typedef __bf16 bf16x8 __attribute__((ext_vector_type(8)));
typedef float f32x4 __attribute__((ext_vector_type(4)));
typedef unsigned int u32x4 __attribute__((ext_vector_type(4)));

#define NB 4
#define NH 12
#define ND 64
#define NN 2048
#define NC 768
// M = NB*NN = 8192 rows; qkv cols = 3*NC = 2304

// async global->LDS, 16B per lane; lds dest = wave-uniform base + lane*16
__device__ __forceinline__ void async_copy16(const bf16_t* g, bf16_t* l) {
    __builtin_amdgcn_global_load_lds((__attribute__((address_space(1))) void*)(void*)g,
                                     (__attribute__((address_space(3))) void*)l, 16, 0, 0);
}

__device__ __forceinline__ unsigned pack_bf2(float a, float b) {
    union { bf16_t e[2]; unsigned u; } t;
    t.e[0] = (bf16_t)a;
    t.e[1] = (bf16_t)b;
    return t.u;
}

// ---------------- merged cast fp32 -> bf16 (3 segments), 4 elems/thread ----------------
__global__ void cast3_kernel(const float* __restrict__ s0, bf16_t* __restrict__ d0, int n0,
                             const float* __restrict__ s1, bf16_t* __restrict__ d1, int n1,
                             const float* __restrict__ s2, bf16_t* __restrict__ d2, int n2) {
    int i = blockIdx.x * blockDim.x + threadIdx.x;   // float4 units
    const float* s;
    bf16_t* d;
    int j;
    if (i < n0)           { s = s0; d = d0; j = i; }
    else if (i < n0 + n1) { s = s1; d = d1; j = i - n0; }
    else if (i < n0 + n1 + n2) { s = s2; d = d2; j = i - n0 - n1; }
    else return;
    float4 v = ((const float4*)s)[j];
    union { bf16_t e[4]; uint2 u; } t;
    t.e[0] = (bf16_t)v.x; t.e[1] = (bf16_t)v.y; t.e[2] = (bf16_t)v.z; t.e[3] = (bf16_t)v.w;
    ((uint2*)d)[j] = t.u;
}

// key permutation: key s (within 64-tile) -> V storage position
// pos bits {c5,c4,c3,c2,c1,c0} = {s5, s3, s2, s4, s1, s0}  (s0,s1 fixed -> +p stays consecutive)
__device__ __forceinline__ int vperm(int s) {
    return (s & 32) | (((s >> 2) & 3) << 3) | (((s >> 4) & 1) << 2) | (s & 3);
}

// GEMM/attn LDS tiles: [rows][8 chunks of 16B], XOR swizzle: data chunk c of row r
// lives at chunk position c ^ (r & 7). Measured conflict-free (SQ_LDS_BANK_CONFLICT=0).

// ---------------- QKV GEMM: [8192,2304] = X[8192,768] @ W[2304,768]^T + b ----------------
// R8/R10 measured-best: capacity-aware XCD chunking — each XCD owns a 16m x 9n rectangle
// (n-fastest): 9 W-panels (1.8 MB) + live X-panels fit its private L2, so panels are read
// from L3/HBM ~once. R11's Q/K operand-swap epilogue regressed (-15us: scattered 16-row
// write fan-out + duplicated MFMA loop body) — reverted. Inner structure frozen (R2-best).
// Q,K out bf16 [B,H,N,D] (Q pre-scaled by D^-0.5*log2e); V out bf16 [B,H,D,N] vperm'd.
__launch_bounds__(256)
__global__ void qkv_gemm_kernel(const bf16_t* __restrict__ X, const bf16_t* __restrict__ W,
                                const float* __restrict__ bias,
                                bf16_t* __restrict__ Q, bf16_t* __restrict__ K, bf16_t* __restrict__ V)
{
    __shared__ __align__(16) bf16_t sA[128 * 64];
    __shared__ __align__(16) bf16_t sB[128 * 64];
    const int tid  = threadIdx.x;
    const int lane = tid & 63;
    const int w    = tid >> 6;
    const int wm   = w & 1, wn = w >> 1;
    const int wg  = blockIdx.y * 64 + blockIdx.x;   // 0..1151
    const int xcd = wg & 7;
    const int idx = wg >> 3;                        // 0..143 = 16m x 9n
    const int m0  = ((xcd >> 1) * 16 + idx / 9) * 128;
    const int n0  = ((xcd & 1) * 9 + idx % 9) * 128;
    const int lrow = lane & 15;
    const int quad = lane >> 4;
    const int arow = lane >> 3;
    const int gch  = (lane & 7) ^ arow;   // swizzled source chunk

    f32x4 zero = {0.f, 0.f, 0.f, 0.f};
    f32x4 acc[4][4];
#pragma unroll
    for (int i = 0; i < 4; ++i)
#pragma unroll
        for (int j = 0; j < 4; ++j) acc[i][j] = zero;

    for (int kt = 0; kt < NC; kt += 64) {
        __syncthreads();
        for (int c = w; c < 16; c += 4) {
            async_copy16(X + (size_t)(m0 + c * 8 + arow) * NC + kt + gch * 8, sA + c * 512);
            async_copy16(W + (size_t)(n0 + c * 8 + arow) * NC + kt + gch * 8, sB + c * 512);
        }
        __syncthreads();
#pragma unroll
        for (int hh = 0; hh < 2; ++hh) {
            bf16x8 af[4], bfr[4];
#pragma unroll
            for (int i = 0; i < 4; ++i) {
                int r = wm * 64 + i * 16 + lrow;
                af[i] = *(const bf16x8*)(sA + r * 64 + (((hh * 4 + quad) ^ (r & 7)) * 8));
            }
#pragma unroll
            for (int j = 0; j < 4; ++j) {
                int r = wn * 64 + j * 16 + lrow;
                bfr[j] = *(const bf16x8*)(sB + r * 64 + (((hh * 4 + quad) ^ (r & 7)) * 8));
            }
#pragma unroll
            for (int i = 0; i < 4; ++i)
#pragma unroll
                for (int j = 0; j < 4; ++j)
                    acc[i][j] = __builtin_amdgcn_mfma_f32_16x16x32_bf16(af[i], bfr[j], acc[i][j], 0, 0, 0);
        }
    }

    const int colbase = n0 + wn * 64;       // 64-aligned -> t3,h uniform per wave
    const int t3 = colbase / NC;
    const int h  = (colbase % NC) / ND;
    const float qscale = 0.125f * 1.44269504088896340736f; // D^-0.5 * log2(e)

#pragma unroll
    for (int j = 0; j < 4; ++j) {
        const int d  = j * 16 + lrow;
        const float bv = bias[colbase + d];
#pragma unroll
        for (int i = 0; i < 4; ++i) {
            const int rowg = m0 + wm * 64 + i * 16 + quad * 4;
            const int bb = rowg >> 11;
            const int nn = rowg & 2047;
            if (t3 == 2) {
                union { bf16_t e[4]; uint2 u; } pk;
#pragma unroll
                for (int p = 0; p < 4; ++p) pk.e[p] = (bf16_t)(acc[i][j][p] + bv);
                const int pos = (nn & ~63) | vperm(nn & 63);
                *(uint2*)(V + ((size_t)(bb * NH + h) * ND + d) * NN + pos) = pk.u;
            } else {
                bf16_t* outb = t3 ? K : Q;
#pragma unroll
                for (int p = 0; p < 4; ++p) {
                    float val = acc[i][j][p] + bv;
                    if (t3 == 0) val *= qscale;
                    outb[((size_t)(bb * NH + h) * NN + nn + p) * ND + d] = (bf16_t)val;
                }
            }
        }
    }
}

// ---------------- flash attention v6 (R5/R8/R10 measured-best, frozen): 8 waves x 16 q-rows ----------------
// R5 = 69.6us best; R8/R10 reproduced 70.1/71.6. Tri-buffer + counted vmcnt, conflict-free
// 16x16 LDS pattern. Across R0-R9 absolute pipe-busy conserved (VALU ~32us, MFMA ~24us)
// under 8 structural variants => HIP-level plateau. FROZEN.
#define WAIT_BAR(N)                                              \
    asm volatile("s_waitcnt vmcnt(" #N ")" ::: "memory");        \
    __builtin_amdgcn_sched_barrier(0);                           \
    __builtin_amdgcn_s_barrier();                                \
    __builtin_amdgcn_sched_barrier(0);

#define STAGE(BUF)                                               \
    {                                                            \
        async_copy16(kp, sK[BUF] + w * 512);                     \
        async_copy16(vp, sV[BUF] + w * 512);                     \
        kp += (size_t)64 * ND; vp += 64;                         \
    }

#define ATTN_COMPUTE(CUR)                                                                            \
    {                                                                                                \
        const bf16_t* sKh = sK[CUR];                                                                 \
        const bf16_t* sVh = sV[CUR];                                                                 \
        f32x4 s[4];                                                                                  \
        __builtin_amdgcn_s_setprio(1);                                                               \
        _Pragma("unroll")                                                                            \
        for (int blk = 0; blk < 4; ++blk) {                                                          \
            bf16x8 a0 = *(const bf16x8*)(sKh + off[blk][0]);                                         \
            bf16x8 a1 = *(const bf16x8*)(sKh + off[blk][1]);                                         \
            f32x4 z = zero;                                                                          \
            z = __builtin_amdgcn_mfma_f32_16x16x32_bf16(a0, qb0, z, 0, 0, 0);                        \
            z = __builtin_amdgcn_mfma_f32_16x16x32_bf16(a1, qb1, z, 0, 0, 0);                        \
            s[blk] = z;                                                                              \
        }                                                                                            \
        __builtin_amdgcn_s_setprio(0);                                                               \
        u32x4 pu0 = {0, 0, 0, 0}, pu1 = {0, 0, 0, 0};                                                \
        _Pragma("unroll")                                                                            \
        for (int blk = 0; blk < 4; ++blk) {                                                          \
            float e0 = __builtin_amdgcn_exp2f(s[blk][0]);                                            \
            float e1 = __builtin_amdgcn_exp2f(s[blk][1]);                                            \
            float e2 = __builtin_amdgcn_exp2f(s[blk][2]);                                            \
            float e3 = __builtin_amdgcn_exp2f(s[blk][3]);                                            \
            unsigned lo = pack_bf2(e0, e1), hi = pack_bf2(e2, e3);                                   \
            if (blk == 0)      { pu0[0] = lo; pu0[1] = hi; }                                         \
            else if (blk == 1) { pu0[2] = lo; pu0[3] = hi; }                                         \
            else if (blk == 2) { pu1[0] = lo; pu1[1] = hi; }                                         \
            else               { pu1[2] = lo; pu1[3] = hi; }                                         \
        }                                                                                            \
        bf16x8 pe0 = __builtin_bit_cast(bf16x8, pu0);                                                \
        bf16x8 pe1 = __builtin_bit_cast(bf16x8, pu1);                                                \
        __builtin_amdgcn_s_setprio(1);                                                               \
        lacc = __builtin_amdgcn_mfma_f32_16x16x32_bf16(ones, pe0, lacc, 0, 0, 0);                    \
        lacc = __builtin_amdgcn_mfma_f32_16x16x32_bf16(ones, pe1, lacc, 0, 0, 0);                    \
        _Pragma("unroll")                                                                            \
        for (int db = 0; db < 4; ++db) {                                                             \
            bf16x8 v0 = *(const bf16x8*)(sVh + off[db][0]);                                          \
            bf16x8 v1 = *(const bf16x8*)(sVh + off[db][1]);                                          \
            o[db] = __builtin_amdgcn_mfma_f32_16x16x32_bf16(v0, pe0, o[db], 0, 0, 0);                \
            o[db] = __builtin_amdgcn_mfma_f32_16x16x32_bf16(v1, pe1, o[db], 0, 0, 0);                \
        }                                                                                            \
        __builtin_amdgcn_s_setprio(0);                                                               \
    }

__launch_bounds__(512, 6)
__global__ void attn_kernel(const bf16_t* __restrict__ Q, const bf16_t* __restrict__ K,
                            const bf16_t* __restrict__ Vt, bf16_t* __restrict__ O)
{
    __shared__ __align__(16) bf16_t sK[3][64 * 64];
    __shared__ __align__(16) bf16_t sV[3][64 * 64];   // [d][pos]
    bf16_t* sQ = sK[0];   // Q tile (16 KB) overlays sK[0..1] during init
    const int tid  = threadIdx.x;
    const int lane = tid & 63;
    const int w    = tid >> 6;          // 0..7
    const int qt   = blockIdx.x;
    const int h    = blockIdx.y;
    const int b    = blockIdx.z;
    const int lrow = lane & 15;
    const int quad = lane >> 4;
    const int arow = lane >> 3;
    const int gch  = (lane & 7) ^ arow;
    const size_t head_off = (size_t)(b * NH + h) * NN * ND;
    const bf16_t* qh = Q  + head_off;
    const bf16_t* kh = K  + head_off;
    const bf16_t* vh = Vt + head_off;   // [d][n]

    // stage Q tile [128 x 64]: wave w stages chunks 2w, 2w+1
#pragma unroll
    for (int c = 0; c < 2; ++c)
        async_copy16(qh + (size_t)(qt * 128 + (w * 2 + c) * 8 + arow) * ND + gch * 8,
                     sQ + (w * 2 + c) * 512);
    __syncthreads();

    bf16x8 qb0, qb1;
    {
        int r = w * 16 + lrow;
        qb0 = *(const bf16x8*)(sQ + r * 64 + (((0 * 4 + quad) ^ (r & 7)) * 8));
        qb1 = *(const bf16x8*)(sQ + r * 64 + (((1 * 4 + quad) ^ (r & 7)) * 8));
    }
    __syncthreads();   // all waves done reading Q before K staging overwrites it

    // ones A-frag for the l row-sum MFMA
    bf16x8 ones;
#pragma unroll
    for (int p = 0; p < 8; ++p) ones[p] = (bf16_t)1.0f;

    // frag offsets (elements), rows blk*16+lrow, two 32-k halves
    int off[4][2];
#pragma unroll
    for (int blk = 0; blk < 4; ++blk) {
        int r = blk * 16 + lrow;
        off[blk][0] = r * 64 + ((quad ^ (r & 7)) * 8);
        off[blk][1] = r * 64 + (((4 + quad) ^ (r & 7)) * 8);
    }

    f32x4 zero = {0.f, 0.f, 0.f, 0.f};
    f32x4 o[4];
#pragma unroll
    for (int db = 0; db < 4; ++db) o[db] = zero;
    f32x4 lacc = zero;

    // staging: wave w covers rows [w*8, w*8+8) of each 64-row step tile
    const bf16_t* kp = kh + (size_t)(w * 8 + arow) * ND + gch * 8;
    const bf16_t* vp = vh + (size_t)(w * 8 + arow) * NN + gch * 8;

    // prologue: stage tiles 0,1 into bufs 0,1; wait only for tile 0 (tile 1 stays in flight)
    STAGE(0);
    STAGE(1);
    WAIT_BAR(2);

    int cur = 0;
    for (int it = 0; it < NN / 64 - 2; ++it) {
        int nxt = cur + 2; if (nxt >= 3) nxt -= 3;
        STAGE(nxt);                 // tile it+2; outstanding: 4 (tiles it+1, it+2)
        ATTN_COMPUTE(cur);          // tile it
        WAIT_BAR(2);                // my tile-(it+1) loads retired; it+2 stays in flight
        cur = (cur + 1 == 3) ? 0 : cur + 1;
    }
    // tile NN/64-2: nothing left to stage; ensure final tile landed before last step
    ATTN_COMPUTE(cur);
    WAIT_BAR(0);
    cur = (cur + 1 == 3) ? 0 : cur + 1;
    ATTN_COMPUTE(cur);

    // write attn out bf16 [B,N,C], col = h*64 + d; 4 consecutive d per store
    {
        const float rl = 1.0f / lacc[0];
        const int n = qt * 128 + w * 16 + lrow;
        const size_t rowoff = ((size_t)(b * NN + n)) * NC + h * ND;
#pragma unroll
        for (int db = 0; db < 4; ++db) {
            union { bf16_t e[4]; uint2 u; } pk;
#pragma unroll
            for (int p = 0; p < 4; ++p) pk.e[p] = (bf16_t)(o[db][p] * rl);
            *(uint2*)(O + rowoff + db * 16 + quad * 4) = pk.u;
        }
    }
}

// ---------------- proj GEMM: out[8192,768] = A[8192,768] @ W[768,768]^T + b (fp32) ----------------
// R8/R10 measured-best: 128x128 tiles, BK=64 single-buffered, scalar fp32 stores. Grid
// (64,6) = 384 wgs. Capacity-aware XCD chunking: each XCD owns 8m x 6n (n-fastest): full
// W (1.2 MB) + 8 A-panels (1.6 MB) = 2.8 MB, fully L2-resident. FROZEN.
__launch_bounds__(256)
__global__ void proj_gemm_kernel(const bf16_t* __restrict__ A, const bf16_t* __restrict__ W,
                                 const float* __restrict__ bias, float* __restrict__ out)
{
    __shared__ __align__(16) bf16_t sA[128 * 64];
    __shared__ __align__(16) bf16_t sB[128 * 64];
    const int tid  = threadIdx.x;
    const int lane = tid & 63;
    const int w    = tid >> 6;
    const int wm   = w & 1, wn = w >> 1;
    const int wg  = blockIdx.y * 64 + blockIdx.x;   // 0..383
    const int xcd = wg & 7;
    const int idx = wg >> 3;                        // 0..47 = 8m x 6n
    const int m0  = (xcd * 8 + idx / 6) * 128;
    const int n0  = (idx % 6) * 128;
    const int lrow = lane & 15;
    const int quad = lane >> 4;
    const int arow = lane >> 3;
    const int gch  = (lane & 7) ^ arow;

    f32x4 zero = {0.f, 0.f, 0.f, 0.f};
    f32x4 acc[4][4];
#pragma unroll
    for (int i = 0; i < 4; ++i)
#pragma unroll
        for (int j = 0; j < 4; ++j) acc[i][j] = zero;

    for (int kt = 0; kt < NC; kt += 64) {
        __syncthreads();
        for (int c = w; c < 16; c += 4) {
            async_copy16(A + (size_t)(m0 + c * 8 + arow) * NC + kt + gch * 8, sA + c * 512);
            async_copy16(W + (size_t)(n0 + c * 8 + arow) * NC + kt + gch * 8, sB + c * 512);
        }
        __syncthreads();
#pragma unroll
        for (int hh = 0; hh < 2; ++hh) {
            bf16x8 af[4], bfr[4];
#pragma unroll
            for (int i = 0; i < 4; ++i) {
                int r = wm * 64 + i * 16 + lrow;
                af[i] = *(const bf16x8*)(sA + r * 64 + (((hh * 4 + quad) ^ (r & 7)) * 8));
            }
#pragma unroll
            for (int j = 0; j < 4; ++j) {
                int r = wn * 64 + j * 16 + lrow;
                bfr[j] = *(const bf16x8*)(sB + r * 64 + (((hh * 4 + quad) ^ (r & 7)) * 8));
            }
#pragma unroll
            for (int i = 0; i < 4; ++i)
#pragma unroll
                for (int j = 0; j < 4; ++j)
                    acc[i][j] = __builtin_amdgcn_mfma_f32_16x16x32_bf16(af[i], bfr[j], acc[i][j], 0, 0, 0);
        }
    }

#pragma unroll
    for (int j = 0; j < 4; ++j) {
        const int colg = n0 + wn * 64 + j * 16 + lrow;
        const float bv = bias[colg];
#pragma unroll
        for (int i = 0; i < 4; ++i) {
            const int rowg = m0 + wm * 64 + i * 16 + quad * 4;
#pragma unroll
            for (int p = 0; p < 4; ++p)
                out[(size_t)(rowg + p) * NC + colg] = acc[i][j][p] + bv;
        }
    }
}

extern "C" void kernel_launch(void* const* d_in, const int* in_sizes, int n_in,
                              void* d_out, int out_size, void* d_ws, size_t ws_size,
                              hipStream_t stream) {
    const float* x      = (const float*)d_in[0];
    const float* qkv_w  = (const float*)d_in[1];
    const float* qkv_b  = (const float*)d_in[2];
    const float* proj_w = (const float*)d_in[3];
    const float* proj_b = (const float*)d_in[4];
    float* out = (float*)d_out;

    char* ws = (char*)d_ws;
    bf16_t* xb    = (bf16_t*)ws; ws += (size_t)8192 * 768 * 2;
    bf16_t* wqkv  = (bf16_t*)ws; ws += (size_t)2304 * 768 * 2;
    bf16_t* wproj = (bf16_t*)ws; ws += (size_t)768 * 768 * 2;
    bf16_t* qb    = (bf16_t*)ws; ws += (size_t)NB * NH * NN * ND * 2;  // [B,H,N,D]
    bf16_t* kb    = (bf16_t*)ws; ws += (size_t)NB * NH * NN * ND * 2;  // [B,H,N,D]
    bf16_t* vb    = (bf16_t*)ws; ws += (size_t)NB * NH * NN * ND * 2;  // [B,H,D,N] permuted
    bf16_t* ab    = (bf16_t*)ws; ws += (size_t)8192 * 768 * 2;         // attn out [B,N,C]

    const int c0 = 8192 * 768 / 4, c1 = 2304 * 768 / 4, c2 = 768 * 768 / 4;
    cast3_kernel<<<(c0 + c1 + c2 + 255) / 256, 256, 0, stream>>>(x, xb, c0, qkv_w, wqkv, c1, proj_w, wproj, c2);

    qkv_gemm_kernel<<<dim3(8192 / 128, 2304 / 128), 256, 0, stream>>>(xb, wqkv, qkv_b, qb, kb, vb);
    attn_kernel<<<dim3(NN / 128, NH, NB), 512, 0, stream>>>(qb, kb, vb, ab);
    proj_gemm_kernel<<<dim3(8192 / 128, 768 / 128), 256, 0, stream>>>(ab, wproj, proj_b, out);
}